// Round 10
// baseline (75.275 us; speedup 1.0000x reference)
//
#include <hip/hip_runtime.h>
#include <hip/hip_bf16.h>
#include <math.h>

// Problem dims (fixed by setup_inputs)
constexpr int B = 4, C = 256, H = 128, W = 128, N = 4096, A = 5;
constexpr int HWs = H * W;
constexpr float AROUND_R = 0.1f;
constexpr int NP = B * N;  // 16384

// ---------- bf16 helpers ----------
__device__ __forceinline__ float ulo(unsigned u) {
    union { unsigned i; float f; } x; x.i = u << 16; return x.f;
}
__device__ __forceinline__ float uhi(unsigned u) {
    union { unsigned i; float f; } x; x.i = u & 0xffff0000u; return x.f;
}
__device__ __forceinline__ float red64(float v) {
    #pragma unroll
    for (int off = 32; off > 0; off >>= 1)
        v += __shfl_xor(v, off);
    return v;
}

// ---------- fp8 e4m3fn helpers (HW path on gfx950, software fallback) ----------
#if __has_builtin(__builtin_amdgcn_cvt_pk_f32_fp8) && __has_builtin(__builtin_amdgcn_cvt_pk_fp8_f32)
#define FP8_HW 1
#endif

__device__ __forceinline__ unsigned enc_fp8_sw(float x) {
    unsigned s = (__float_as_uint(x) >> 31) << 7;
    float ax = fminf(fabsf(x), 448.0f);
    if (!(ax >= 0x1p-10f)) return s;
    int e = (int)((__float_as_uint(ax) >> 23) & 0xff) - 127;
    e = e < -6 ? -6 : e;
    float q = rintf(ldexpf(ax, 3 - e));
    int iq = (int)q;
    if (iq >= 16) { iq = 8; e += 1; }
    unsigned enc = (iq >= 8) ? (((unsigned)(e + 7) << 3) | (unsigned)(iq - 8))
                             : (unsigned)iq;
    return s | enc;
}
__device__ __forceinline__ float dec_fp8_sw(unsigned u) {
    unsigned s = u >> 7, E = (u >> 3) & 0xf, M = u & 7;
    float v = E ? __uint_as_float(((E + 120u) << 23) | (M << 20)) : (float)M * 0x1p-9f;
    return s ? -v : v;
}
__device__ __forceinline__ unsigned pack4_fp8(float a0, float a1, float a2, float a3) {
#ifdef FP8_HW
    int w = __builtin_amdgcn_cvt_pk_fp8_f32(a0, a1, 0, false);
    w = __builtin_amdgcn_cvt_pk_fp8_f32(a2, a3, w, true);
    return (unsigned)w;
#else
    return enc_fp8_sw(a0) | (enc_fp8_sw(a1) << 8) | (enc_fp8_sw(a2) << 16) | (enc_fp8_sw(a3) << 24);
#endif
}
__device__ __forceinline__ void fp8x4_to_f32(unsigned u, float* f) {
#ifdef FP8_HW
    auto lo = __builtin_amdgcn_cvt_pk_f32_fp8((int)u, false);
    auto hi = __builtin_amdgcn_cvt_pk_f32_fp8((int)u, true);
    f[0] = lo[0]; f[1] = lo[1]; f[2] = hi[0]; f[3] = hi[1];
#else
    f[0] = dec_fp8_sw(u & 0xff); f[1] = dec_fp8_sw((u >> 8) & 0xff);
    f[2] = dec_fp8_sw((u >> 16) & 0xff); f[3] = dec_fp8_sw(u >> 24);
#endif
}

// ---------- shared sample math: corner indices + masked bilinear weights ----------
__device__ __forceinline__ void corner_math(float gx0, float gy0, float2 aov,
                                            int* id, float* wg) {
    float gx = fminf(fmaxf(gx0 + (aov.x * 2.0f - 0.5f) * (2.0f * AROUND_R), -1.0f), 1.0f);
    float gy = fminf(fmaxf(gy0 + (aov.y * 2.0f - 0.5f) * (2.0f * AROUND_R), -1.0f), 1.0f);
    float x = (gx + 1.0f) * (W * 0.5f) - 0.5f;
    float y = (gy + 1.0f) * (H * 0.5f) - 0.5f;
    float fx0 = floorf(x), fy0 = floorf(y);
    float wx1 = x - fx0, wy1 = y - fy0;
    float wx0 = 1.0f - wx1, wy0 = 1.0f - wy1;
    int ix0 = (int)fx0, iy0 = (int)fy0, ix1 = ix0 + 1, iy1 = iy0 + 1;
    bool vx0 = (ix0 >= 0) & (ix0 < W), vx1 = (ix1 >= 0) & (ix1 < W);
    bool vy0 = (iy0 >= 0) & (iy0 < H), vy1 = (iy1 >= 0) & (iy1 < H);
    int cx0 = min(max(ix0, 0), W - 1), cx1 = min(max(ix1, 0), W - 1);
    int cy0 = min(max(iy0, 0), H - 1), cy1 = min(max(iy1, 0), H - 1);
    id[0] = cy0 * W + cx0; id[1] = cy0 * W + cx1;
    id[2] = cy1 * W + cx0; id[3] = cy1 * W + cx1;
    wg[0] = (vx0 && vy0) ? wx0 * wy0 : 0.0f;
    wg[1] = (vx1 && vy0) ? wx1 * wy0 : 0.0f;
    wg[2] = (vx0 && vy1) ? wx0 * wy1 : 0.0f;
    wg[3] = (vx1 && vy1) ? wx1 * wy1 : 0.0f;
}

// ---------- K1: transpose x1 [B,C,HW] f32 -> [B,HW,C] fp8 (proven ~14us) ----------
__global__ __launch_bounds__(256) void transpose_x1_fp8(const float* __restrict__ in,
                                                        unsigned* __restrict__ outw) {
    constexpr int TILE = 32;
    __shared__ float t[TILE][C + 1];
    const int tilesPerB = HWs / TILE;  // 512
    int bx = blockIdx.x;
    int b  = bx / tilesPerB;
    int hw0 = (bx % tilesPerB) * TILE;
    int tid  = threadIdx.x;
    int hw_l = tid & 31;
    int cg   = tid >> 5;

    const float* src = in + (size_t)b * C * HWs;
    #pragma unroll
    for (int ci = 0; ci < C / 8; ++ci) {
        int c = ci * 8 + cg;
        t[hw_l][c] = src[(size_t)c * HWs + hw0 + hw_l];
    }
    __syncthreads();
    unsigned* dst = outw + ((size_t)b * HWs + hw0) * (C / 4);
    int dq = tid & 63, pg = tid >> 6;
    #pragma unroll
    for (int it = 0; it < 8; ++it) {
        int pix = it * 4 + pg;
        float a0 = t[pix][dq * 4 + 0], a1 = t[pix][dq * 4 + 1];
        float a2 = t[pix][dq * 4 + 2], a3 = t[pix][dq * 4 + 3];
        dst[(size_t)pix * (C / 4) + dq] = pack4_fp8(a0, a1, a2, a3);
    }
}

// ---------- K2: sim + softmax -> per-point weights (standalone, no LDS) ----------
__global__ __launch_bounds__(256) void sim_softmax(
    const unsigned char* __restrict__ x1f8,  // [B,HW,C] fp8 (from K1)
    const float* __restrict__ pf,            // [B,N,C]
    const float* __restrict__ pts,           // [B,N,2]
    const float* __restrict__ ao,            // [B,A,N,2]
    float* __restrict__ wout)                // [NP,8] softmax weights (5 used)
{
    int tid = threadIdx.x, lane = tid & 63, wave = tid >> 6;
    int p = blockIdx.x * 4 + wave;
    int b = p >> 12, n = p & (N - 1);
    size_t pn = (size_t)p;

    float2 g0 = *reinterpret_cast<const float2*>(pts + pn * 2);
    float2 aov[A];
    #pragma unroll
    for (int a = 0; a < A; ++a)
        aov[a] = *reinterpret_cast<const float2*>(ao + (((size_t)b * A + a) * N + n) * 2);

    float4 rep4 = *reinterpret_cast<const float4*>(pf + pn * C + lane * 4);

    int   sidx[A][4];
    float swgt[A][4];
    #pragma unroll
    for (int a = 0; a < A; ++a) {
        int id[4]; float wg[4];
        corner_math(g0.x, g0.y, aov[a], id, wg);
        #pragma unroll
        for (int k = 0; k < 4; ++k) {
            sidx[a][k] = __builtin_amdgcn_readfirstlane(id[k]);
            swgt[a][k] = wg[k];
        }
    }

    const unsigned char* xb = x1f8 + (size_t)b * HWs * C;
    unsigned xv[A][4];
    #pragma unroll
    for (int a = 0; a < A; ++a)
        #pragma unroll
        for (int k = 0; k < 4; ++k)
            xv[a][k] = *reinterpret_cast<const unsigned*>(xb + (size_t)sidx[a][k] * C + lane * 4);

    float na2 = rep4.x * rep4.x + rep4.y * rep4.y + rep4.z * rep4.z + rep4.w * rep4.w;
    float dt[A], nb[A];
    #pragma unroll
    for (int a = 0; a < A; ++a) {
        float f0 = 0.f, f1 = 0.f, f2 = 0.f, f3 = 0.f;
        #pragma unroll
        for (int k = 0; k < 4; ++k) {
            float w = swgt[a][k];
            float c4[4];
            fp8x4_to_f32(xv[a][k], c4);
            f0 += w * c4[0]; f1 += w * c4[1]; f2 += w * c4[2]; f3 += w * c4[3];
        }
        dt[a] = rep4.x * f0 + rep4.y * f1 + rep4.z * f2 + rep4.w * f3;
        nb[a] = f0 * f0 + f1 * f1 + f2 * f2 + f3 * f3;
    }

    na2 = red64(na2);
    #pragma unroll
    for (int a = 0; a < A; ++a) dt[a] = red64(dt[a]);
    #pragma unroll
    for (int a = 0; a < A; ++a) nb[a] = red64(nb[a]);
    float na = fmaxf(sqrtf(na2), 1e-8f);

    float sim[A];
    #pragma unroll
    for (int a = 0; a < A; ++a)
        sim[a] = dt[a] / (na * fmaxf(sqrtf(nb[a]), 1e-8f));

    float m = sim[0];
    #pragma unroll
    for (int a = 1; a < A; ++a) m = fmaxf(m, sim[a]);
    float e[A], s = 0.f;
    #pragma unroll
    for (int a = 0; a < A; ++a) { e[a] = __expf(sim[a] - m); s += e[a]; }
    float inv = 1.0f / s;

    if (lane == 0) {
        *reinterpret_cast<float4*>(wout + pn * 8) =
            make_float4(e[0] * inv, e[1] * inv, e[2] * inv, e[3] * inv);
        wout[pn * 8 + 4] = e[4] * inv;
    }
}

// ---------- K3: transpose pe [B,C,HW] f32 -> [B,HW,C] bf16 (proven ~16us) ----------
__global__ __launch_bounds__(256) void transpose_pe_bf16(const float* __restrict__ in,
                                                         __hip_bfloat16* __restrict__ out) {
    constexpr int TILE = 32;
    __shared__ float t[TILE][C + 1];
    const int tilesPerB = HWs / TILE;
    int bx = blockIdx.x;
    int b  = bx / tilesPerB;
    int hw0 = (bx % tilesPerB) * TILE;
    int tid  = threadIdx.x;
    int hw_l = tid & 31;
    int cg   = tid >> 5;

    const float* src = in + (size_t)b * C * HWs;
    #pragma unroll
    for (int ci = 0; ci < C / 8; ++ci) {
        int c = ci * 8 + cg;
        t[hw_l][c] = src[(size_t)c * HWs + hw0 + hw_l];
    }
    __syncthreads();
    __hip_bfloat16* dst = out + ((size_t)b * HWs + hw0) * C;
    #pragma unroll
    for (int hwi = 0; hwi < 32; ++hwi) {
        dst[(size_t)hwi * C + tid] = __float2bfloat16(t[hwi][tid]);
    }
}

// ---------- K4: emb gather + output (r9-proven ~13.5us) ----------
__global__ __launch_bounds__(256) void k3_emb(
    const ushort* __restrict__ pebf,  // [B,HW,C] bf16
    const float* __restrict__ pf,     // [B,N,C]
    const float* __restrict__ pts,    // [B,N,2]
    const float* __restrict__ ao,     // [B,A,N,2]
    const float* __restrict__ wsm,    // [NP,8]
    float* __restrict__ out)          // [B,N,C]
{
    int tid = threadIdx.x, lane = tid & 63, wave = tid >> 6;
    int p = blockIdx.x * 4 + wave;
    int b = p >> 12, n = p & (N - 1);
    size_t pn = (size_t)p;

    float2 g0 = *reinterpret_cast<const float2*>(pts + pn * 2);
    float2 aov[A];
    #pragma unroll
    for (int a = 0; a < A; ++a)
        aov[a] = *reinterpret_cast<const float2*>(ao + (((size_t)b * A + a) * N + n) * 2);

    float4 w03 = *reinterpret_cast<const float4*>(wsm + pn * 8);
    float  w4  = wsm[pn * 8 + 4];
    float wa[A] = {w03.x, w03.y, w03.z, w03.w, w4};

    int   sidx[A][4];
    float cwt[A][4];
    #pragma unroll
    for (int a = 0; a < A; ++a) {
        int id[4]; float wg[4];
        corner_math(g0.x, g0.y, aov[a], id, wg);
        #pragma unroll
        for (int k = 0; k < 4; ++k) {
            sidx[a][k] = __builtin_amdgcn_readfirstlane(id[k]);
            cwt[a][k] = wa[a] * wg[k];
        }
    }

    const ushort* pb = pebf + (size_t)b * HWs * C;
    uint2 pv[A][4];
    #pragma unroll
    for (int a = 0; a < A; ++a)
        #pragma unroll
        for (int k = 0; k < 4; ++k)
            pv[a][k] = *reinterpret_cast<const uint2*>(pb + (size_t)sidx[a][k] * C + lane * 4);

    float4 rep4 = *reinterpret_cast<const float4*>(pf + pn * C + lane * 4);
    float o0 = rep4.x, o1 = rep4.y, o2 = rep4.z, o3 = rep4.w;
    #pragma unroll
    for (int a = 0; a < A; ++a) {
        #pragma unroll
        for (int k = 0; k < 4; ++k) {
            float c = cwt[a][k];
            unsigned u0 = pv[a][k].x, u1 = pv[a][k].y;
            o0 += c * ulo(u0); o1 += c * uhi(u0);
            o2 += c * ulo(u1); o3 += c * uhi(u1);
        }
    }
    *reinterpret_cast<float4*>(out + pn * C + lane * 4) = make_float4(o0, o1, o2, o3);
}

extern "C" void kernel_launch(void* const* d_in, const int* in_sizes, int n_in,
                              void* d_out, int out_size, void* d_ws, size_t ws_size,
                              hipStream_t stream) {
    const float* x1  = (const float*)d_in[0];
    const float* pf  = (const float*)d_in[1];
    const float* pts = (const float*)d_in[2];
    const float* pe  = (const float*)d_in[3];
    const float* ao  = (const float*)d_in[4];
    float* out = (float*)d_out;

    // ws: x1f8 [B,HW,C] fp8 = 16.78 MB | pebf [B,HW,C] bf16 = 33.55 MB | wsm [NP*8] f32
    unsigned* x1f8w = (unsigned*)d_ws;
    __hip_bfloat16* pebf = (__hip_bfloat16*)((char*)d_ws + (size_t)B * HWs * C);
    float* wsm = (float*)((char*)d_ws + (size_t)B * HWs * C + (size_t)B * HWs * C * 2);

    int tblocks = B * (HWs / 32);  // 2048

    // Order: x1T -> sim (x1f8 cache-hot) -> peT -> emb (pebf cache-hot)
    transpose_x1_fp8<<<tblocks, 256, 0, stream>>>(x1, x1f8w);
    sim_softmax<<<NP / 4, 256, 0, stream>>>((const unsigned char*)x1f8w, pf, pts, ao, wsm);
    transpose_pe_bf16<<<tblocks, 256, 0, stream>>>(pe, pebf);
    k3_emb<<<NP / 4, 256, 0, stream>>>((const ushort*)pebf, pf, pts, ao, wsm, out);
}

// Round 11
// 68.433 us; speedup vs baseline: 1.1000x; 1.1000x over previous
//
#include <hip/hip_runtime.h>
#include <hip/hip_bf16.h>
#include <math.h>

// Problem dims (fixed by setup_inputs)
constexpr int B = 4, C = 256, H = 128, W = 128, N = 4096, A = 5;
constexpr int HWs = H * W;
constexpr float AROUND_R = 0.1f;
constexpr int NP = B * N;  // 16384

typedef float     f2 __attribute__((ext_vector_type(2)));
typedef _Float16  h2 __attribute__((ext_vector_type(2)));

// ---------- helpers ----------
__device__ __forceinline__ f2 bfpair(unsigned u) {  // 2 bf16 -> f2
    f2 r;
    r[0] = __uint_as_float(u << 16);
    r[1] = __uint_as_float(u & 0xffff0000u);
    return r;
}

// ---------- fp8 e4m3fn helpers (HW path on gfx950, software fallback) ----------
#if __has_builtin(__builtin_amdgcn_cvt_pk_f32_fp8) && __has_builtin(__builtin_amdgcn_cvt_pk_fp8_f32)
#define FP8_HW 1
#endif

__device__ __forceinline__ unsigned enc_fp8_sw(float x) {
    unsigned s = (__float_as_uint(x) >> 31) << 7;
    float ax = fminf(fabsf(x), 448.0f);
    if (!(ax >= 0x1p-10f)) return s;
    int e = (int)((__float_as_uint(ax) >> 23) & 0xff) - 127;
    e = e < -6 ? -6 : e;
    float q = rintf(ldexpf(ax, 3 - e));
    int iq = (int)q;
    if (iq >= 16) { iq = 8; e += 1; }
    unsigned enc = (iq >= 8) ? (((unsigned)(e + 7) << 3) | (unsigned)(iq - 8))
                             : (unsigned)iq;
    return s | enc;
}
__device__ __forceinline__ float dec_fp8_sw(unsigned u) {
    unsigned s = u >> 7, E = (u >> 3) & 0xf, M = u & 7;
    float v = E ? __uint_as_float(((E + 120u) << 23) | (M << 20)) : (float)M * 0x1p-9f;
    return s ? -v : v;
}
__device__ __forceinline__ unsigned pack4_fp8(float a0, float a1, float a2, float a3) {
#ifdef FP8_HW
    int w = __builtin_amdgcn_cvt_pk_fp8_f32(a0, a1, 0, false);
    w = __builtin_amdgcn_cvt_pk_fp8_f32(a2, a3, w, true);
    return (unsigned)w;
#else
    return enc_fp8_sw(a0) | (enc_fp8_sw(a1) << 8) | (enc_fp8_sw(a2) << 16) | (enc_fp8_sw(a3) << 24);
#endif
}
__device__ __forceinline__ void fp8x4_to_f2(unsigned u, f2& lo, f2& hi) {
#ifdef FP8_HW
    lo = __builtin_amdgcn_cvt_pk_f32_fp8((int)u, false);
    hi = __builtin_amdgcn_cvt_pk_f32_fp8((int)u, true);
#else
    lo[0] = dec_fp8_sw(u & 0xff);         lo[1] = dec_fp8_sw((u >> 8) & 0xff);
    hi[0] = dec_fp8_sw((u >> 16) & 0xff); hi[1] = dec_fp8_sw(u >> 24);
#endif
}

// ---------- shared sample math: corner indices + masked bilinear weights ----------
__device__ __forceinline__ void corner_math(float gx0, float gy0, float2 aov,
                                            int* id, float* wg) {
    float gx = fminf(fmaxf(gx0 + (aov.x * 2.0f - 0.5f) * (2.0f * AROUND_R), -1.0f), 1.0f);
    float gy = fminf(fmaxf(gy0 + (aov.y * 2.0f - 0.5f) * (2.0f * AROUND_R), -1.0f), 1.0f);
    float x = (gx + 1.0f) * (W * 0.5f) - 0.5f;
    float y = (gy + 1.0f) * (H * 0.5f) - 0.5f;
    float fx0 = floorf(x), fy0 = floorf(y);
    float wx1 = x - fx0, wy1 = y - fy0;
    float wx0 = 1.0f - wx1, wy0 = 1.0f - wy1;
    int ix0 = (int)fx0, iy0 = (int)fy0, ix1 = ix0 + 1, iy1 = iy0 + 1;
    bool vx0 = (ix0 >= 0) & (ix0 < W), vx1 = (ix1 >= 0) & (ix1 < W);
    bool vy0 = (iy0 >= 0) & (iy0 < H), vy1 = (iy1 >= 0) & (iy1 < H);
    int cx0 = min(max(ix0, 0), W - 1), cx1 = min(max(ix1, 0), W - 1);
    int cy0 = min(max(iy0, 0), H - 1), cy1 = min(max(iy1, 0), H - 1);
    id[0] = cy0 * W + cx0; id[1] = cy0 * W + cx1;
    id[2] = cy1 * W + cx0; id[3] = cy1 * W + cx1;
    wg[0] = (vx0 && vy0) ? wx0 * wy0 : 0.0f;
    wg[1] = (vx1 && vy0) ? wx1 * wy0 : 0.0f;
    wg[2] = (vx0 && vy1) ? wx0 * wy1 : 0.0f;
    wg[3] = (vx1 && vy1) ? wx1 * wy1 : 0.0f;
}

// ---------- K1: transpose x1 [B,C,HW] f32 -> [B,HW,C] fp8 (proven ~14us) ----------
__global__ __launch_bounds__(256) void transpose_x1_fp8(const float* __restrict__ in,
                                                        unsigned* __restrict__ outw) {
    constexpr int TILE = 32;
    __shared__ float t[TILE][C + 1];
    const int tilesPerB = HWs / TILE;  // 512
    int bx = blockIdx.x;
    int b  = bx / tilesPerB;
    int hw0 = (bx % tilesPerB) * TILE;
    int tid  = threadIdx.x;
    int hw_l = tid & 31;
    int cg   = tid >> 5;

    const float* src = in + (size_t)b * C * HWs;
    #pragma unroll
    for (int ci = 0; ci < C / 8; ++ci) {
        int c = ci * 8 + cg;
        t[hw_l][c] = src[(size_t)c * HWs + hw0 + hw_l];
    }
    __syncthreads();
    unsigned* dst = outw + ((size_t)b * HWs + hw0) * (C / 4);
    int dq = tid & 63, pg = tid >> 6;
    #pragma unroll
    for (int it = 0; it < 8; ++it) {
        int pix = it * 4 + pg;
        float a0 = t[pix][dq * 4 + 0], a1 = t[pix][dq * 4 + 1];
        float a2 = t[pix][dq * 4 + 2], a3 = t[pix][dq * 4 + 3];
        dst[(size_t)pix * (C / 4) + dq] = pack4_fp8(a0, a1, a2, a3);
    }
}

// ---------- K2: transpose pe [B,C,HW] f32 -> [B,HW,C] bf16 (proven ~16us) ----------
__global__ __launch_bounds__(256) void transpose_pe_bf16(const float* __restrict__ in,
                                                         __hip_bfloat16* __restrict__ out) {
    constexpr int TILE = 32;
    __shared__ float t[TILE][C + 1];
    const int tilesPerB = HWs / TILE;
    int bx = blockIdx.x;
    int b  = bx / tilesPerB;
    int hw0 = (bx % tilesPerB) * TILE;
    int tid  = threadIdx.x;
    int hw_l = tid & 31;
    int cg   = tid >> 5;

    const float* src = in + (size_t)b * C * HWs;
    #pragma unroll
    for (int ci = 0; ci < C / 8; ++ci) {
        int c = ci * 8 + cg;
        t[hw_l][c] = src[(size_t)c * HWs + hw0 + hw_l];
    }
    __syncthreads();
    __hip_bfloat16* dst = out + ((size_t)b * HWs + hw0) * C;
    #pragma unroll
    for (int hwi = 0; hwi < 32; ++hwi) {
        dst[(size_t)hwi * C + tid] = __float2bfloat16(t[hwi][tid]);
    }
}

// ---------- K3: monolith (r7 structure) with packed f32 math + packed f16 reductions --
__global__ __launch_bounds__(256) void soft_align_v7(
    const unsigned char* __restrict__ x1f8,  // [B,HW,C] fp8
    const ushort* __restrict__ pebf,         // [B,HW,C] bf16
    const float* __restrict__ pf,            // [B,N,C]
    const float* __restrict__ pts,           // [B,N,2]
    const float* __restrict__ ao,            // [B,A,N,2]
    float* __restrict__ out)                 // [B,N,C]
{
    int tid = threadIdx.x, lane = tid & 63, wave = tid >> 6;
    int p = blockIdx.x * 4 + wave;
    int b = p >> 12, n = p & (N - 1);
    size_t pn = (size_t)p;

    float2 g0 = *reinterpret_cast<const float2*>(pts + pn * 2);
    float2 aov[A];
    #pragma unroll
    for (int a = 0; a < A; ++a)
        aov[a] = *reinterpret_cast<const float2*>(ao + (((size_t)b * A + a) * N + n) * 2);

    float4 rep4 = *reinterpret_cast<const float4*>(pf + pn * C + lane * 4);
    f2 rep01; rep01[0] = rep4.x; rep01[1] = rep4.y;
    f2 rep23; rep23[0] = rep4.z; rep23[1] = rep4.w;

    // --- corner math: wave-uniform indices -> SGPR, masked weights ---
    int   sidx[A][4];
    float swgt[A][4];
    #pragma unroll
    for (int a = 0; a < A; ++a) {
        int id[4]; float wg[4];
        corner_math(g0.x, g0.y, aov[a], id, wg);
        #pragma unroll
        for (int k = 0; k < 4; ++k) {
            sidx[a][k] = __builtin_amdgcn_readfirstlane(id[k]);
            swgt[a][k] = wg[k];
        }
    }

    // --- issue ALL x1 loads (20 x dword) then ALL pe loads (20 x uint2) ---
    const unsigned char* xb = x1f8 + (size_t)b * HWs * C;
    const ushort*        pb = pebf + (size_t)b * HWs * C;
    unsigned xv[A][4];
    #pragma unroll
    for (int a = 0; a < A; ++a)
        #pragma unroll
        for (int k = 0; k < 4; ++k)
            xv[a][k] = *reinterpret_cast<const unsigned*>(xb + (size_t)sidx[a][k] * C + lane * 4);
    uint2 pv[A][4];
    #pragma unroll
    for (int a = 0; a < A; ++a)
        #pragma unroll
        for (int k = 0; k < 4; ++k)
            pv[a][k] = *reinterpret_cast<const uint2*>(pb + (size_t)sidx[a][k] * C + lane * 4);

    // --- consume x1: packed f2 accumulate, dot & norm partials ---
    f2 nacc = {0.f, 0.f};
    nacc = __builtin_elementwise_fma(rep01, rep01, nacc);
    nacc = __builtin_elementwise_fma(rep23, rep23, nacc);
    float naa = nacc[0] + nacc[1];

    unsigned rpk[A];  // packed {dt, nb} f16 per sample
    #pragma unroll
    for (int a = 0; a < A; ++a) {
        f2 f01 = {0.f, 0.f}, f23 = {0.f, 0.f};
        #pragma unroll
        for (int k = 0; k < 4; ++k) {
            f2 lo, hi;
            fp8x4_to_f2(xv[a][k], lo, hi);
            float w = swgt[a][k];
            f2 w2; w2[0] = w; w2[1] = w;
            f01 = __builtin_elementwise_fma(w2, lo, f01);
            f23 = __builtin_elementwise_fma(w2, hi, f23);
        }
        f2 d = {0.f, 0.f};
        d = __builtin_elementwise_fma(rep01, f01, d);
        d = __builtin_elementwise_fma(rep23, f23, d);
        f2 q = {0.f, 0.f};
        q = __builtin_elementwise_fma(f01, f01, q);
        q = __builtin_elementwise_fma(f23, f23, q);
        float dt = d[0] + d[1];
        float nb = q[0] + q[1];
        rpk[a] = __builtin_bit_cast(unsigned, __builtin_amdgcn_cvt_pkrtz(dt, nb));
    }

    // --- reductions: 5 packed-f16 chains + 1 f32 chain, interleaved ---
    #pragma unroll
    for (int off = 32; off > 0; off >>= 1) {
        naa += __shfl_xor(naa, off);
        #pragma unroll
        for (int a = 0; a < A; ++a) {
            h2 cur = __builtin_bit_cast(h2, rpk[a]);
            h2 oth = __builtin_bit_cast(h2, (unsigned)__shfl_xor(rpk[a], off));
            h2 sum = cur + oth;
            rpk[a] = __builtin_bit_cast(unsigned, sum);
        }
    }
    float na = fmaxf(sqrtf(naa), 1e-8f);

    float sim[A];
    #pragma unroll
    for (int a = 0; a < A; ++a) {
        h2 r = __builtin_bit_cast(h2, rpk[a]);
        float dt = (float)r[0], nb = (float)r[1];
        sim[a] = dt / (na * fmaxf(sqrtf(nb), 1e-8f));
    }

    // --- softmax over A (uniform across lanes) ---
    float m = sim[0];
    #pragma unroll
    for (int a = 1; a < A; ++a) m = fmaxf(m, sim[a]);
    float e[A], s = 0.f;
    #pragma unroll
    for (int a = 0; a < A; ++a) { e[a] = __expf(sim[a] - m); s += e[a]; }
    float inv = 1.0f / s;

    // --- emb: packed f2 deferred accumulation from the 20 held pe registers ---
    f2 o01 = rep01, o23 = rep23;
    #pragma unroll
    for (int a = 0; a < A; ++a) {
        float wa = e[a] * inv;
        #pragma unroll
        for (int k = 0; k < 4; ++k) {
            float c = wa * swgt[a][k];
            f2 c2; c2[0] = c; c2[1] = c;
            o01 = __builtin_elementwise_fma(c2, bfpair(pv[a][k].x), o01);
            o23 = __builtin_elementwise_fma(c2, bfpair(pv[a][k].y), o23);
        }
    }
    *reinterpret_cast<float4*>(out + pn * C + lane * 4) =
        make_float4(o01[0], o01[1], o23[0], o23[1]);
}

extern "C" void kernel_launch(void* const* d_in, const int* in_sizes, int n_in,
                              void* d_out, int out_size, void* d_ws, size_t ws_size,
                              hipStream_t stream) {
    const float* x1  = (const float*)d_in[0];
    const float* pf  = (const float*)d_in[1];
    const float* pts = (const float*)d_in[2];
    const float* pe  = (const float*)d_in[3];
    const float* ao  = (const float*)d_in[4];
    float* out = (float*)d_out;

    // ws: x1f8 [B,HW,C] fp8 = 16.78 MB | pebf [B,HW,C] bf16 = 33.55 MB
    unsigned* x1f8w = (unsigned*)d_ws;
    __hip_bfloat16* pebf = (__hip_bfloat16*)((char*)d_ws + (size_t)B * HWs * C);

    int tblocks = B * (HWs / 32);  // 2048
    transpose_x1_fp8 <<<tblocks, 256, 0, stream>>>(x1, x1f8w);
    transpose_pe_bf16<<<tblocks, 256, 0, stream>>>(pe, pebf);
    soft_align_v7<<<NP / 4, 256, 0, stream>>>((const unsigned char*)x1f8w,
                                              (const ushort*)pebf, pf, pts, ao, out);
}

// Round 12
// 64.844 us; speedup vs baseline: 1.1609x; 1.0554x over previous
//
#include <hip/hip_runtime.h>
#include <hip/hip_bf16.h>
#include <math.h>

// Problem dims (fixed by setup_inputs)
constexpr int B = 4, C = 256, H = 128, W = 128, N = 4096, A = 5;
constexpr int HWs = H * W;
constexpr float AROUND_R = 0.1f;
constexpr int NP = B * N;  // 16384

typedef float     f2 __attribute__((ext_vector_type(2)));
typedef _Float16  h2 __attribute__((ext_vector_type(2)));

// ---------- helpers ----------
__device__ __forceinline__ f2 bfpair(unsigned u) {  // 2 bf16 -> f2
    f2 r;
    r[0] = __uint_as_float(u << 16);
    r[1] = __uint_as_float(u & 0xffff0000u);
    return r;
}

// ---------- fp8 e4m3fn helpers (HW path on gfx950, software fallback) ----------
#if __has_builtin(__builtin_amdgcn_cvt_pk_f32_fp8) && __has_builtin(__builtin_amdgcn_cvt_pk_fp8_f32)
#define FP8_HW 1
#endif

__device__ __forceinline__ unsigned enc_fp8_sw(float x) {
    unsigned s = (__float_as_uint(x) >> 31) << 7;
    float ax = fminf(fabsf(x), 448.0f);
    if (!(ax >= 0x1p-10f)) return s;
    int e = (int)((__float_as_uint(ax) >> 23) & 0xff) - 127;
    e = e < -6 ? -6 : e;
    float q = rintf(ldexpf(ax, 3 - e));
    int iq = (int)q;
    if (iq >= 16) { iq = 8; e += 1; }
    unsigned enc = (iq >= 8) ? (((unsigned)(e + 7) << 3) | (unsigned)(iq - 8))
                             : (unsigned)iq;
    return s | enc;
}
__device__ __forceinline__ float dec_fp8_sw(unsigned u) {
    unsigned s = u >> 7, E = (u >> 3) & 0xf, M = u & 7;
    float v = E ? __uint_as_float(((E + 120u) << 23) | (M << 20)) : (float)M * 0x1p-9f;
    return s ? -v : v;
}
__device__ __forceinline__ unsigned pack4_fp8(float a0, float a1, float a2, float a3) {
#ifdef FP8_HW
    int w = __builtin_amdgcn_cvt_pk_fp8_f32(a0, a1, 0, false);
    w = __builtin_amdgcn_cvt_pk_fp8_f32(a2, a3, w, true);
    return (unsigned)w;
#else
    return enc_fp8_sw(a0) | (enc_fp8_sw(a1) << 8) | (enc_fp8_sw(a2) << 16) | (enc_fp8_sw(a3) << 24);
#endif
}
__device__ __forceinline__ void fp8x4_to_f2(unsigned u, f2& lo, f2& hi) {
#ifdef FP8_HW
    lo = __builtin_amdgcn_cvt_pk_f32_fp8((int)u, false);
    hi = __builtin_amdgcn_cvt_pk_f32_fp8((int)u, true);
#else
    lo[0] = dec_fp8_sw(u & 0xff);         lo[1] = dec_fp8_sw((u >> 8) & 0xff);
    hi[0] = dec_fp8_sw((u >> 16) & 0xff); hi[1] = dec_fp8_sw(u >> 24);
#endif
}

// ---------- shared sample math: corner indices + masked bilinear weights ----------
__device__ __forceinline__ void corner_math(float gx0, float gy0, float2 aov,
                                            int* id, float* wg) {
    float gx = fminf(fmaxf(gx0 + (aov.x * 2.0f - 0.5f) * (2.0f * AROUND_R), -1.0f), 1.0f);
    float gy = fminf(fmaxf(gy0 + (aov.y * 2.0f - 0.5f) * (2.0f * AROUND_R), -1.0f), 1.0f);
    float x = (gx + 1.0f) * (W * 0.5f) - 0.5f;
    float y = (gy + 1.0f) * (H * 0.5f) - 0.5f;
    float fx0 = floorf(x), fy0 = floorf(y);
    float wx1 = x - fx0, wy1 = y - fy0;
    float wx0 = 1.0f - wx1, wy0 = 1.0f - wy1;
    int ix0 = (int)fx0, iy0 = (int)fy0, ix1 = ix0 + 1, iy1 = iy0 + 1;
    bool vx0 = (ix0 >= 0) & (ix0 < W), vx1 = (ix1 >= 0) & (ix1 < W);
    bool vy0 = (iy0 >= 0) & (iy0 < H), vy1 = (iy1 >= 0) & (iy1 < H);
    int cx0 = min(max(ix0, 0), W - 1), cx1 = min(max(ix1, 0), W - 1);
    int cy0 = min(max(iy0, 0), H - 1), cy1 = min(max(iy1, 0), H - 1);
    id[0] = cy0 * W + cx0; id[1] = cy0 * W + cx1;
    id[2] = cy1 * W + cx0; id[3] = cy1 * W + cx1;
    wg[0] = (vx0 && vy0) ? wx0 * wy0 : 0.0f;
    wg[1] = (vx1 && vy0) ? wx1 * wy0 : 0.0f;
    wg[2] = (vx0 && vy1) ? wx0 * wy1 : 0.0f;
    wg[3] = (vx1 && vy1) ? wx1 * wy1 : 0.0f;
}

// ---------- K1: transpose x1 [B,C,HW] f32 -> [B,HW,C] fp8 (proven ~14us) ----------
__global__ __launch_bounds__(256) void transpose_x1_fp8(const float* __restrict__ in,
                                                        unsigned* __restrict__ outw) {
    constexpr int TILE = 32;
    __shared__ float t[TILE][C + 1];
    const int tilesPerB = HWs / TILE;  // 512
    int bx = blockIdx.x;
    int b  = bx / tilesPerB;
    int hw0 = (bx % tilesPerB) * TILE;
    int tid  = threadIdx.x;
    int hw_l = tid & 31;
    int cg   = tid >> 5;

    const float* src = in + (size_t)b * C * HWs;
    #pragma unroll
    for (int ci = 0; ci < C / 8; ++ci) {
        int c = ci * 8 + cg;
        t[hw_l][c] = src[(size_t)c * HWs + hw0 + hw_l];
    }
    __syncthreads();
    unsigned* dst = outw + ((size_t)b * HWs + hw0) * (C / 4);
    int dq = tid & 63, pg = tid >> 6;
    #pragma unroll
    for (int it = 0; it < 8; ++it) {
        int pix = it * 4 + pg;
        float a0 = t[pix][dq * 4 + 0], a1 = t[pix][dq * 4 + 1];
        float a2 = t[pix][dq * 4 + 2], a3 = t[pix][dq * 4 + 3];
        dst[(size_t)pix * (C / 4) + dq] = pack4_fp8(a0, a1, a2, a3);
    }
}

// ---------- K2: transpose pe [B,C,HW] f32 -> [B,HW,C] bf16 (proven ~16us) ----------
__global__ __launch_bounds__(256) void transpose_pe_bf16(const float* __restrict__ in,
                                                         __hip_bfloat16* __restrict__ out) {
    constexpr int TILE = 32;
    __shared__ float t[TILE][C + 1];
    const int tilesPerB = HWs / TILE;
    int bx = blockIdx.x;
    int b  = bx / tilesPerB;
    int hw0 = (bx % tilesPerB) * TILE;
    int tid  = threadIdx.x;
    int hw_l = tid & 31;
    int cg   = tid >> 5;

    const float* src = in + (size_t)b * C * HWs;
    #pragma unroll
    for (int ci = 0; ci < C / 8; ++ci) {
        int c = ci * 8 + cg;
        t[hw_l][c] = src[(size_t)c * HWs + hw0 + hw_l];
    }
    __syncthreads();
    __hip_bfloat16* dst = out + ((size_t)b * HWs + hw0) * C;
    #pragma unroll
    for (int hwi = 0; hwi < 32; ++hwi) {
        dst[(size_t)hwi * C + tid] = __float2bfloat16(t[hwi][tid]);
    }
}

// ---------- K3: monolith, TWO points per wave (32 lanes / point, 8 ch/lane) ----------
__global__ __launch_bounds__(256) void soft_align_v8(
    const unsigned char* __restrict__ x1f8,  // [B,HW,C] fp8
    const ushort* __restrict__ pebf,         // [B,HW,C] bf16
    const float* __restrict__ pf,            // [B,N,C]
    const float* __restrict__ pts,           // [B,N,2]
    const float* __restrict__ ao,            // [B,A,N,2]
    float* __restrict__ out)                 // [B,N,C]
{
    int tid = threadIdx.x, lane = tid & 63, wave = tid >> 6;
    int h  = lane >> 5;           // which point within the wave
    int cl = lane & 31;           // channel group: 8cl..8cl+7
    int p = blockIdx.x * 8 + wave * 2 + h;
    int b = p >> 12, n = p & (N - 1);
    size_t pn = (size_t)p;

    float2 g0 = *reinterpret_cast<const float2*>(pts + pn * 2);
    float2 aov[A];
    #pragma unroll
    for (int a = 0; a < A; ++a)
        aov[a] = *reinterpret_cast<const float2*>(ao + (((size_t)b * A + a) * N + n) * 2);

    const float* repp = pf + pn * C + cl * 8;
    float4 r0 = *reinterpret_cast<const float4*>(repp);
    float4 r1 = *reinterpret_cast<const float4*>(repp + 4);
    f2 rep[4];
    rep[0][0] = r0.x; rep[0][1] = r0.y; rep[1][0] = r0.z; rep[1][1] = r0.w;
    rep[2][0] = r1.x; rep[2][1] = r1.y; rep[3][0] = r1.z; rep[3][1] = r1.w;

    // --- corner math (per half-wave; uniform within the half) ---
    int   sidx[A][4];
    float swgt[A][4];
    #pragma unroll
    for (int a = 0; a < A; ++a)
        corner_math(g0.x, g0.y, aov[a], sidx[a], swgt[a]);

    // --- issue x1 gathers: one uint2/lane per corner (covers both points) ---
    const unsigned char* xb = x1f8 + (size_t)b * HWs * C;
    const ushort*        pb = pebf + (size_t)b * HWs * C;
    uint2 xv[A][4];
    #pragma unroll
    for (int a = 0; a < A; ++a)
        #pragma unroll
        for (int k = 0; k < 4; ++k)
            xv[a][k] = *reinterpret_cast<const uint2*>(xb + (size_t)sidx[a][k] * C + cl * 8);
    // --- issue pe gathers: one uint4/lane per corner ---
    uint4 pv[A][4];
    #pragma unroll
    for (int a = 0; a < A; ++a)
        #pragma unroll
        for (int k = 0; k < 4; ++k)
            pv[a][k] = *reinterpret_cast<const uint4*>(pb + (size_t)sidx[a][k] * C + cl * 8);

    // --- consume x1: packed f2 accumulate, dot & norm partials ---
    f2 nacc = {0.f, 0.f};
    #pragma unroll
    for (int j = 0; j < 4; ++j) nacc = __builtin_elementwise_fma(rep[j], rep[j], nacc);
    float naa = nacc[0] + nacc[1];

    unsigned rpk[A];  // packed {dt, nb} f16 per sample
    #pragma unroll
    for (int a = 0; a < A; ++a) {
        f2 f[4] = {{0.f,0.f},{0.f,0.f},{0.f,0.f},{0.f,0.f}};
        #pragma unroll
        for (int k = 0; k < 4; ++k) {
            float w = swgt[a][k];
            f2 w2; w2[0] = w; w2[1] = w;
            f2 lo, hi;
            fp8x4_to_f2(xv[a][k].x, lo, hi);
            f[0] = __builtin_elementwise_fma(w2, lo, f[0]);
            f[1] = __builtin_elementwise_fma(w2, hi, f[1]);
            fp8x4_to_f2(xv[a][k].y, lo, hi);
            f[2] = __builtin_elementwise_fma(w2, lo, f[2]);
            f[3] = __builtin_elementwise_fma(w2, hi, f[3]);
        }
        f2 d = {0.f, 0.f}, q = {0.f, 0.f};
        #pragma unroll
        for (int j = 0; j < 4; ++j) {
            d = __builtin_elementwise_fma(rep[j], f[j], d);
            q = __builtin_elementwise_fma(f[j], f[j], q);
        }
        rpk[a] = __builtin_bit_cast(unsigned,
                     __builtin_amdgcn_cvt_pkrtz(d[0] + d[1], q[0] + q[1]));
    }

    // --- reductions within each 32-lane half: 1 f32 + 5 packed-f16 chains ---
    #pragma unroll
    for (int off = 16; off > 0; off >>= 1) {
        naa += __shfl_xor(naa, off);
        #pragma unroll
        for (int a = 0; a < A; ++a) {
            h2 cur = __builtin_bit_cast(h2, rpk[a]);
            h2 oth = __builtin_bit_cast(h2, (unsigned)__shfl_xor(rpk[a], off));
            h2 sum = cur + oth;
            rpk[a] = __builtin_bit_cast(unsigned, sum);
        }
    }
    float na = fmaxf(sqrtf(naa), 1e-8f);

    float sim[A];
    #pragma unroll
    for (int a = 0; a < A; ++a) {
        h2 r = __builtin_bit_cast(h2, rpk[a]);
        sim[a] = (float)r[0] / (na * fmaxf(sqrtf((float)r[1]), 1e-8f));
    }

    // --- softmax over A (uniform within half) ---
    float m = sim[0];
    #pragma unroll
    for (int a = 1; a < A; ++a) m = fmaxf(m, sim[a]);
    float e[A], s = 0.f;
    #pragma unroll
    for (int a = 0; a < A; ++a) { e[a] = __expf(sim[a] - m); s += e[a]; }
    float inv = 1.0f / s;

    // --- emb: packed f2 deferred accumulation from the held pe registers ---
    f2 o[4] = {rep[0], rep[1], rep[2], rep[3]};
    #pragma unroll
    for (int a = 0; a < A; ++a) {
        float wa = e[a] * inv;
        #pragma unroll
        for (int k = 0; k < 4; ++k) {
            float c = wa * swgt[a][k];
            f2 c2; c2[0] = c; c2[1] = c;
            o[0] = __builtin_elementwise_fma(c2, bfpair(pv[a][k].x), o[0]);
            o[1] = __builtin_elementwise_fma(c2, bfpair(pv[a][k].y), o[1]);
            o[2] = __builtin_elementwise_fma(c2, bfpair(pv[a][k].z), o[2]);
            o[3] = __builtin_elementwise_fma(c2, bfpair(pv[a][k].w), o[3]);
        }
    }
    float* op = out + pn * C + cl * 8;
    *reinterpret_cast<float4*>(op)     = make_float4(o[0][0], o[0][1], o[1][0], o[1][1]);
    *reinterpret_cast<float4*>(op + 4) = make_float4(o[2][0], o[2][1], o[3][0], o[3][1]);
}

extern "C" void kernel_launch(void* const* d_in, const int* in_sizes, int n_in,
                              void* d_out, int out_size, void* d_ws, size_t ws_size,
                              hipStream_t stream) {
    const float* x1  = (const float*)d_in[0];
    const float* pf  = (const float*)d_in[1];
    const float* pts = (const float*)d_in[2];
    const float* pe  = (const float*)d_in[3];
    const float* ao  = (const float*)d_in[4];
    float* out = (float*)d_out;

    // ws: x1f8 [B,HW,C] fp8 = 16.78 MB | pebf [B,HW,C] bf16 = 33.55 MB
    unsigned* x1f8w = (unsigned*)d_ws;
    __hip_bfloat16* pebf = (__hip_bfloat16*)((char*)d_ws + (size_t)B * HWs * C);

    int tblocks = B * (HWs / 32);  // 2048
    transpose_x1_fp8 <<<tblocks, 256, 0, stream>>>(x1, x1f8w);
    transpose_pe_bf16<<<tblocks, 256, 0, stream>>>(pe, pebf);
    soft_align_v8<<<NP / 8, 256, 0, stream>>>((const unsigned char*)x1f8w,
                                              (const ushort*)pebf, pf, pts, ao, out);
}